// Round 5
// baseline (83.325 us; speedup 1.0000x reference)
//
#include <hip/hip_runtime.h>
#include <hip/hip_cooperative_groups.h>

namespace cg = cooperative_groups;

// DirectionalScan: B=4, H=64, W=64, D=512, N=8
// out = ((scan_h(x) + scan_v(x)) @ Wp^T) + b_proj
#define BB 4
#define HH 64
#define WW 64
#define DD 512
#define NS 8
#define MROWS (BB * HH * WW)  // 16384

typedef __attribute__((ext_vector_type(8))) __bf16 bf16x8;
typedef __attribute__((ext_vector_type(4))) float f32x4;

__device__ inline short f2bf(float f) {  // RNE f32 -> bf16 bits
  unsigned u = __float_as_uint(f);
  return (short)((u + 0x7fff + ((u >> 16) & 1)) >> 16);
}
__device__ inline float bf2f(short s) {
  return __uint_as_float(((unsigned)(unsigned short)s) << 16);
}

// One cooperative kernel, 256 blocks x 512 threads (1 block/CU @ 128KB LDS).
// Phase A: block=(b,w) scans over h, writes y_h bf16; also converts Wp->bf16.
// grid.sync()
// Phase B: block=(b,h) scans over w, adds y_h, Y-tile -> swizzled LDS,
//          then 64x512x512 GEMM with stage-early double-buffered Bs.
__global__ __launch_bounds__(512, 2) void fused_all(
    const float* __restrict__ x, const float* __restrict__ A,
    const float* __restrict__ Bm, const float* __restrict__ Cm,
    const float* __restrict__ Dsk, const float* __restrict__ Wp,
    const float* __restrict__ bias, short* __restrict__ yh,
    short* __restrict__ wb, float* __restrict__ out) {
  __shared__ __align__(16) short Ys[64 * DD];     // 64 KB  [w][d^((w&7)<<3)]
  __shared__ __align__(16) short Bs[2][DD * 32];  // 2x32KB [n][k^((n&3)<<3)]

  const int tid = (int)threadIdx.x;  // 0..511
  const int lane = tid & 63;
  const int wid = tid >> 6;  // 0..7
  const int d = tid;         // channel, same role in both phases

  // per-channel params (shared by both phases)
  float a[NS], bm[NS], cm[NS], s[NS];
#pragma unroll
  for (int i = 0; i < NS; i += 4) {
    float4 t;
    t = *(const float4*)&A[(size_t)d * NS + i];
    a[i] = t.x; a[i + 1] = t.y; a[i + 2] = t.z; a[i + 3] = t.w;
    t = *(const float4*)&Bm[(size_t)d * NS + i];
    bm[i] = t.x; bm[i + 1] = t.y; bm[i + 2] = t.z; bm[i + 3] = t.w;
    t = *(const float4*)&Cm[(size_t)d * NS + i];
    cm[i] = t.x; cm[i + 1] = t.y; cm[i + 2] = t.z; cm[i + 3] = t.w;
  }
  const float dk = Dsk[d];

  // ---------------- phase A: scan_h + Wp->bf16 conv ----------------
  {
    const int b = (int)blockIdx.x >> 6;
    const int w = (int)blockIdx.x & 63;
    size_t base = ((size_t)b * HH * WW + w) * DD + d;
    const size_t step = (size_t)WW * DD;
#pragma unroll
    for (int i = 0; i < NS; ++i) s[i] = 0.f;

    // fused Wp conversion: 2 elems per thread covers all 512*512
    {
      const int gi = ((int)blockIdx.x * 512 + tid) * 2;
      const float2 v = *(const float2*)&Wp[gi];
      short2 r2;
      r2.x = f2bf(v.x);
      r2.y = f2bf(v.y);
      *(short2*)&wb[gi] = r2;
    }

    float hx[2][8];
#pragma unroll
    for (int i = 0; i < 8; ++i) hx[0][i] = x[base + (size_t)i * step];
#pragma unroll 2
    for (int c = 0; c < 8; ++c) {
      const int cur = c & 1, nxt = cur ^ 1;
      const size_t nbase = base + 8 * step;
      if (c < 7) {
#pragma unroll
        for (int i = 0; i < 8; ++i) hx[nxt][i] = x[nbase + (size_t)i * step];
      }
#pragma unroll
      for (int i = 0; i < 8; ++i) {
        const float xv = hx[cur][i];
        float acc = dk * xv;
#pragma unroll
        for (int n = 0; n < NS; ++n) {
          s[n] = fmaf(a[n], s[n], bm[n] * xv);
          acc = fmaf(s[n], cm[n], acc);
        }
        yh[base + (size_t)i * step] = f2bf(acc);
      }
      base = nbase;
    }
  }

  // prefetch phase-B x chunk 0 (input x: safe before the grid sync)
  const int m0 = (int)blockIdx.x * 64;  // block = b*64 + h -> 64 contig rows
  size_t vbase = (size_t)m0 * DD + d;
  float xs[2][8], yp[2][8];
#pragma unroll
  for (int i = 0; i < 8; ++i) xs[0][i] = x[vbase + (size_t)i * DD];

  cg::this_grid().sync();  // y_h & wb complete, device-visible

  // stage Bs K-slab ks into buf (linear LDS dest, inverse-swizzled source)
  auto stageB = [&](int ks, int buf) {
    const int k0 = ks * 32;
#pragma unroll
    for (int c = 0; c < 4; ++c) {
      const int chunk = wid * 4 + c;           // 0..31, 16 rows each
      const int n = chunk * 16 + (lane >> 2);  // Wp row 0..511
      const int kslot = ((lane & 3) ^ (n & 3)) << 3;
      const short* g = &wb[(size_t)n * DD + k0 + kslot];
      __builtin_amdgcn_global_load_lds(
          (const __attribute__((address_space(1))) unsigned int*)g,
          (__attribute__((address_space(3))) unsigned int*)((char*)&Bs[buf][0] +
                                                            chunk * 1024),
          16, 0, 0);
    }
  };
  stageB(0, 0);  // lands during the scan below

  // ---------------- phase B scan over w ----------------
#pragma unroll
  for (int i = 0; i < 8; ++i) yp[0][i] = bf2f(yh[vbase + (size_t)i * DD]);
#pragma unroll
  for (int i = 0; i < NS; ++i) s[i] = 0.f;

#pragma unroll 2
  for (int c = 0; c < 8; ++c) {
    const int cur = c & 1, nxt = cur ^ 1;
    const size_t nbase = vbase + 8 * DD;
    if (c < 7) {
#pragma unroll
      for (int i = 0; i < 8; ++i) xs[nxt][i] = x[nbase + (size_t)i * DD];
#pragma unroll
      for (int i = 0; i < 8; ++i) yp[nxt][i] = bf2f(yh[nbase + (size_t)i * DD]);
    }
#pragma unroll
    for (int i = 0; i < 8; ++i) {
      const int w = c * 8 + i;
      const float xv = xs[cur][i];
      float acc = fmaf(dk, xv, yp[cur][i]);
#pragma unroll
      for (int n = 0; n < NS; ++n) {
        s[n] = fmaf(a[n], s[n], bm[n] * xv);
        acc = fmaf(s[n], cm[n], acc);
      }
      Ys[w * DD + (d ^ ((w & 7) << 3))] = f2bf(acc);
    }
    vbase = nbase;
  }

  __syncthreads();  // Ys complete; Bs[0] drained (vmcnt0 within barrier)

  // ---------------- GEMM: out[m0..+63][0..511] = Ys @ Wb^T + bias -------
  f32x4 acc4[4][4];
#pragma unroll
  for (int m = 0; m < 4; ++m)
#pragma unroll
    for (int n = 0; n < 4; ++n) acc4[m][n] = (f32x4){0.f, 0.f, 0.f, 0.f};

  const int fr = lane & 15;
  const int kfr = (lane >> 4) * 8;  // 0,8,16,24

  int cur = 0;
  for (int ks = 0; ks < 16; ++ks) {  // K-steps of 32
    if (ks < 15) stageB(ks + 1, cur ^ 1);  // overlaps this step's compute
    bf16x8 af[4], bfv[4];
    const int kg = ks * 32 + kfr;  // global k (multiple of 8)
#pragma unroll
    for (int m = 0; m < 4; ++m) {
      const int r = m * 16 + fr;  // Y row 0..63
      af[m] = *(const bf16x8*)(const void*)&Ys[r * DD + (kg ^ ((r & 7) << 3))];
    }
#pragma unroll
    for (int n = 0; n < 4; ++n) {
      const int nn = wid * 64 + n * 16 + fr;  // out col 0..511
      bfv[n] = *(const bf16x8*)(const void*)&Bs[cur][nn * 32 +
                                                     (kfr ^ ((nn & 3) << 3))];
    }
#pragma unroll
    for (int m = 0; m < 4; ++m)
#pragma unroll
      for (int n = 0; n < 4; ++n)
        acc4[m][n] = __builtin_amdgcn_mfma_f32_16x16x32_bf16(af[m], bfv[n],
                                                             acc4[m][n], 0, 0, 0);
    __syncthreads();  // drains stage(ks+1); all waves done with Bs[cur]
    cur ^= 1;
  }

  // epilogue: D layout col=lane&15, row=(lane>>4)*4+j  [m89 verified]
  const int c16 = lane & 15;
  const int r4 = (lane >> 4) * 4;
#pragma unroll
  for (int m = 0; m < 4; ++m) {
    const int rowb = m0 + m * 16 + r4;
#pragma unroll
    for (int n = 0; n < 4; ++n) {
      const int col = wid * 64 + n * 16 + c16;
      const float bv = bias[col];
#pragma unroll
      for (int j = 0; j < 4; ++j)
        out[(size_t)(rowb + j) * DD + col] = acc4[m][n][j] + bv;
    }
  }
}

// ---------------- launcher ----------------
extern "C" void kernel_launch(void* const* d_in, const int* in_sizes, int n_in,
                              void* d_out, int out_size, void* d_ws,
                              size_t ws_size, hipStream_t stream) {
  const float* x = (const float*)d_in[0];
  const float* A = (const float*)d_in[3];
  const float* Bm = (const float*)d_in[4];
  const float* Cm = (const float*)d_in[5];
  const float* Dsk = (const float*)d_in[6];
  const float* Wp = (const float*)d_in[7];
  const float* bpj = (const float*)d_in[8];
  float* out = (float*)d_out;

  short* yh = (short*)d_ws;                                   // 16 MB bf16 y_h
  short* wb = (short*)((char*)d_ws + (size_t)MROWS * DD * 2);  // 512 KB bf16 Wp

  void* kargs[] = {(void*)&x,   (void*)&A,  (void*)&Bm, (void*)&Cm,
                   (void*)&Dsk, (void*)&Wp, (void*)&bpj, (void*)&yh,
                   (void*)&wb,  (void*)&out};
  hipLaunchCooperativeKernel((void*)fused_all, dim3(BB * HH), dim3(512), kargs,
                             0, stream);
}

// Round 6
// 42.236 us; speedup vs baseline: 1.9728x; 1.9728x over previous
//
#include <hip/hip_runtime.h>

// DirectionalScan: B=4, H=64, W=64, D=512, N=8
// out = ((scan_h(x) + scan_v(x)) @ Wp^T) + b_proj
#define BB 4
#define HH 64
#define WW 64
#define DD 512
#define NS 8
#define MROWS (BB * HH * WW)  // 16384

typedef __attribute__((ext_vector_type(8))) __bf16 bf16x8;
typedef __attribute__((ext_vector_type(4))) float f32x4;

__device__ inline short f2bf(float f) {  // RNE f32 -> bf16 bits
  unsigned u = __float_as_uint(f);
  return (short)((u + 0x7fff + ((u >> 16) & 1)) >> 16);
}
__device__ inline float bf2f(short s) {
  return __uint_as_float(((unsigned)(unsigned short)s) << 16);
}

// one SSM step: update states s[], return C.s + D*x via 3-level tree
// (critical path ~20cyc vs 36 for the serial acc chain)
__device__ inline float ssm_step(float xv, float* s, const float* a,
                                 const float* bm, const float* cm, float dk) {
#pragma unroll
  for (int n = 0; n < NS; ++n) s[n] = fmaf(a[n], s[n], bm[n] * xv);
  float p0 = s[0] * cm[0], p1 = s[1] * cm[1], p2 = s[2] * cm[2],
        p3 = s[3] * cm[3], p4 = s[4] * cm[4], p5 = s[5] * cm[5],
        p6 = s[6] * cm[6], p7 = s[7] * cm[7];
  float q0 = p0 + p1, q1 = p2 + p3, q2 = p4 + p5, q3 = p6 + p7;
  return fmaf(dk, xv, (q0 + q1) + (q2 + q3));
}

// ---------------- kernel 1: scan_h (writes y_h bf16) + fused Wp->bf16 -------
__global__ __launch_bounds__(256) void scan_h_kernel(
    const float* __restrict__ x, const float* __restrict__ A,
    const float* __restrict__ Bm, const float* __restrict__ Cm,
    const float* __restrict__ Dsk, short* __restrict__ y,
    const float* __restrict__ Wp, short* __restrict__ wb) {
  if (blockIdx.x >= 256) {
    const int cid = (blockIdx.x - 256) * 2 + blockIdx.y;  // 0..127
    const int i = (cid * 256 + (int)threadIdx.x) * 8;
    const float4 v0 = *(const float4*)&Wp[i];
    const float4 v1 = *(const float4*)&Wp[i + 4];
    short r[8];
    r[0] = f2bf(v0.x); r[1] = f2bf(v0.y); r[2] = f2bf(v0.z); r[3] = f2bf(v0.w);
    r[4] = f2bf(v1.x); r[5] = f2bf(v1.y); r[6] = f2bf(v1.z); r[7] = f2bf(v1.w);
    *(short4*)&wb[i] = *(short4*)&r[0];
    *(short4*)&wb[i + 4] = *(short4*)&r[4];
    return;
  }

  const int seq = blockIdx.x;  // 0..255 = b*64 + w
  const int d = blockIdx.y * 256 + threadIdx.x;
  const int b = seq >> 6;
  const int r = seq & 63;

  size_t base = ((size_t)b * HH * WW + r) * DD + d;
  const size_t step = (size_t)WW * DD;

  float a[NS], bm[NS], cm[NS], s[NS];
#pragma unroll
  for (int i = 0; i < NS; i += 4) {
    float4 t;
    t = *(const float4*)&A[(size_t)d * NS + i];
    a[i] = t.x; a[i + 1] = t.y; a[i + 2] = t.z; a[i + 3] = t.w;
    t = *(const float4*)&Bm[(size_t)d * NS + i];
    bm[i] = t.x; bm[i + 1] = t.y; bm[i + 2] = t.z; bm[i + 3] = t.w;
    t = *(const float4*)&Cm[(size_t)d * NS + i];
    cm[i] = t.x; cm[i + 1] = t.y; cm[i + 2] = t.z; cm[i + 3] = t.w;
  }
  const float dk = Dsk[d];
#pragma unroll
  for (int i = 0; i < NS; ++i) s[i] = 0.f;

  // 2-chunk-ahead prefetch (4-slot ring, unroll 4 keeps indices static)
  float xs[4][8];
#pragma unroll
  for (int i = 0; i < 8; ++i) xs[0][i] = x[base + (size_t)i * step];
#pragma unroll
  for (int i = 0; i < 8; ++i) xs[1][i] = x[base + (size_t)(8 + i) * step];

#pragma unroll 4
  for (int c = 0; c < 8; ++c) {
    const int cur = c & 3;
    if (c < 6) {
      const size_t pbase = base + 16 * step;
#pragma unroll
      for (int i = 0; i < 8; ++i)
        xs[(c + 2) & 3][i] = x[pbase + (size_t)i * step];
    }
#pragma unroll
    for (int i = 0; i < 8; ++i)
      y[base + (size_t)i * step] = f2bf(ssm_step(xs[cur][i], s, a, bm, cm, dk));
    base += 8 * step;
  }
}

// ------- kernel 2: fused scan_v + y_h add + GEMM(Y @ Wp^T) + bias ----------
// One block per (b,h) = 64 contiguous output rows; 512 threads = 8 waves.
// Phase 1: thread d scans w, adds y_h, writes bf16 Y-tile to swizzled LDS.
// Phase 2: 64x512x512 GEMM. Bs staging is WAVE-PRIVATE (wave wid stages the
// rows it reads) -> barrier-free double-buffered K-loop, counted vmcnt.
__global__ __launch_bounds__(512) void scanv_gemm_kernel(
    const float* __restrict__ x, const float* __restrict__ A,
    const float* __restrict__ Bm, const float* __restrict__ Cm,
    const float* __restrict__ Dsk, const short* __restrict__ yh,
    const short* __restrict__ Wb, const float* __restrict__ bias,
    float* __restrict__ out) {
  __shared__ __align__(16) short Ys[64 * DD];     // 64 KB [w][d^((w&7)<<3)]
  __shared__ __align__(16) short Bs[2][DD * 32];  // 2x32KB [n][k^((n&3)<<3)]

  const int tid = (int)threadIdx.x;  // 0..511
  const int lane = tid & 63;
  const int wid = tid >> 6;  // 0..7
  const int m0 = blockIdx.x * 64;
  const int d = tid;

  // stage Bs K-slab ks (32 wide) into buf. Wave wid writes chunks wid*4..+3
  // = rows wid*64..wid*64+63 — exactly the rows it later reads.
  auto stageB = [&](int ks, int buf) {
    const int k0 = ks * 32;
#pragma unroll
    for (int c = 0; c < 4; ++c) {
      const int chunk = wid * 4 + c;           // 0..31, 16 rows each
      const int n = chunk * 16 + (lane >> 2);  // Wp row
      const int kslot = ((lane & 3) ^ (n & 3)) << 3;
      const short* g = &Wb[(size_t)n * DD + k0 + kslot];
      __builtin_amdgcn_global_load_lds(
          (const __attribute__((address_space(1))) unsigned int*)g,
          (__attribute__((address_space(3))) unsigned int*)((char*)&Bs[buf][0] +
                                                            chunk * 1024),
          16, 0, 0);
    }
  };

  float a[NS], bm[NS], cm[NS], s[NS];
#pragma unroll
  for (int i = 0; i < NS; i += 4) {
    float4 t;
    t = *(const float4*)&A[(size_t)d * NS + i];
    a[i] = t.x; a[i + 1] = t.y; a[i + 2] = t.z; a[i + 3] = t.w;
    t = *(const float4*)&Bm[(size_t)d * NS + i];
    bm[i] = t.x; bm[i + 1] = t.y; bm[i + 2] = t.z; bm[i + 3] = t.w;
    t = *(const float4*)&Cm[(size_t)d * NS + i];
    cm[i] = t.x; cm[i + 1] = t.y; cm[i + 2] = t.z; cm[i + 3] = t.w;
  }
  const float dk = Dsk[d];
#pragma unroll
  for (int i = 0; i < NS; ++i) s[i] = 0.f;

  size_t base = (size_t)m0 * DD + d;
  stageB(0, 0);  // lands under the scan; long done before GEMM

  // 2-chunk-ahead prefetch of x and y_h
  float xs[4][8], yp[4][8];
#pragma unroll
  for (int i = 0; i < 8; ++i) xs[0][i] = x[base + (size_t)i * DD];
#pragma unroll
  for (int i = 0; i < 8; ++i) yp[0][i] = bf2f(yh[base + (size_t)i * DD]);
#pragma unroll
  for (int i = 0; i < 8; ++i) xs[1][i] = x[base + (size_t)(8 + i) * DD];
#pragma unroll
  for (int i = 0; i < 8; ++i) yp[1][i] = bf2f(yh[base + (size_t)(8 + i) * DD]);

#pragma unroll 4
  for (int c = 0; c < 8; ++c) {
    const int cur = c & 3;
    if (c < 6) {
      const size_t pbase = base + 16 * DD;
#pragma unroll
      for (int i = 0; i < 8; ++i)
        xs[(c + 2) & 3][i] = x[pbase + (size_t)i * DD];
#pragma unroll
      for (int i = 0; i < 8; ++i)
        yp[(c + 2) & 3][i] = bf2f(yh[pbase + (size_t)i * DD]);
    }
#pragma unroll
    for (int i = 0; i < 8; ++i) {
      const int w = c * 8 + i;
      const float acc =
          ssm_step(xs[cur][i], s, a, bm, cm, dk) + yp[cur][i];
      Ys[w * DD + (d ^ ((w & 7) << 3))] = f2bf(acc);
    }
    base += 8 * DD;
  }

  __syncthreads();  // Ys complete (only barrier in the kernel)

  // ---- GEMM: out[m0..+63][0..511] = Ys @ Wb^T + bias ----
  f32x4 acc4[4][4];
#pragma unroll
  for (int m = 0; m < 4; ++m)
#pragma unroll
    for (int n = 0; n < 4; ++n) acc4[m][n] = (f32x4){0.f, 0.f, 0.f, 0.f};

  const int fr = lane & 15;
  const int kfr = (lane >> 4) * 8;  // 0,8,16,24

  int cur = 0;
  for (int ks = 0; ks < 16; ++ks) {  // K-steps of 32, double-buffered
    if (ks < 15) {
      stageB(ks + 1, cur ^ 1);
      asm volatile("s_waitcnt vmcnt(4)" ::: "memory");  // stage(ks) done
    } else {
      asm volatile("s_waitcnt vmcnt(0)" ::: "memory");
    }
    __builtin_amdgcn_sched_barrier(0);  // rule #18: fence ds_reads below wait

    bf16x8 af[4], bfv[4];
    const int kg = ks * 32 + kfr;
#pragma unroll
    for (int m = 0; m < 4; ++m) {
      const int r = m * 16 + fr;  // Y row 0..63
      af[m] = *(const bf16x8*)(const void*)&Ys[r * DD + (kg ^ ((r & 7) << 3))];
    }
#pragma unroll
    for (int n = 0; n < 4; ++n) {
      const int nn = wid * 64 + n * 16 + fr;  // out col (wave-private rows)
      bfv[n] = *(const bf16x8*)(const void*)&Bs[cur][nn * 32 +
                                                     (kfr ^ ((nn & 3) << 3))];
    }
#pragma unroll
    for (int m = 0; m < 4; ++m)
#pragma unroll
      for (int n = 0; n < 4; ++n)
        acc4[m][n] = __builtin_amdgcn_mfma_f32_16x16x32_bf16(
            af[m], bfv[n], acc4[m][n], 0, 0, 0);
    __builtin_amdgcn_sched_barrier(0);  // keep iter body intact (WAR safety)
    cur ^= 1;
  }

  // epilogue: D layout col=lane&15, row=(lane>>4)*4+j  [m89 verified]
  const int c16 = lane & 15;
  const int r4 = (lane >> 4) * 4;
#pragma unroll
  for (int m = 0; m < 4; ++m) {
    const int rowb = m0 + m * 16 + r4;
#pragma unroll
    for (int n = 0; n < 4; ++n) {
      const int col = wid * 64 + n * 16 + c16;
      const float bv = bias[col];
#pragma unroll
      for (int j = 0; j < 4; ++j)
        out[(size_t)(rowb + j) * DD + col] = acc4[m][n][j] + bv;
    }
  }
}

// ---------------- launcher ----------------
extern "C" void kernel_launch(void* const* d_in, const int* in_sizes, int n_in,
                              void* d_out, int out_size, void* d_ws,
                              size_t ws_size, hipStream_t stream) {
  const float* x = (const float*)d_in[0];
  const float* A = (const float*)d_in[3];
  const float* Bm = (const float*)d_in[4];
  const float* Cm = (const float*)d_in[5];
  const float* Dsk = (const float*)d_in[6];
  const float* Wp = (const float*)d_in[7];
  const float* bpj = (const float*)d_in[8];
  float* out = (float*)d_out;

  short* yh = (short*)d_ws;                                    // 16 MB bf16 y_h
  short* wb = (short*)((char*)d_ws + (size_t)MROWS * DD * 2);  // 512 KB bf16 Wp

  const dim3 grid_h(256 + 64, DD / 256);
  scan_h_kernel<<<grid_h, 256, 0, stream>>>(x, A, Bm, Cm, Dsk, yh, Wp, wb);

  scanv_gemm_kernel<<<BB * HH, 512, 0, stream>>>(x, A, Bm, Cm, Dsk, yh, wb,
                                                 bpj, out);
}